// Round 5
// baseline (899.100 us; speedup 1.0000x reference)
//
#include <hip/hip_runtime.h>
#include <cstddef>
#include <cstdint>
#include <cmath>

#define V 8000
#define D 256
#define B 64
#define L 64
#define SPLIT 8
#define NCH 200
#define VC 40                      // NCH*VC = V
#define ROW4 (V * D / 4)           // 512000 float4 per batch row

// ws layout (float offsets) — nothing needs host-side zeroing
#define PART_OFF 0         // [B*D]
#define CTX_OFF  16384     // [D]
#define W1_OFF   16640     // [V]
#define W0_OFF   24640     // [V]
#define A_OFF    32640     // [B*V] zeroed by k2
#define P_OFF    544640    // [NCH*B*D] fully overwritten by k4

typedef float f32x4 __attribute__((ext_vector_type(4)));

// ---------------- kernel 1: per-batch masked row mean -> part[b,d] ----------------
__global__ __launch_bounds__(256) void k1_ctx(const int* __restrict__ clist,
                                              const int* __restrict__ clen,
                                              const float* __restrict__ embw,
                                              float* __restrict__ part) {
    int b = blockIdx.x, d = threadIdx.x;
    __shared__ int cl[L];
    if (d < L) cl[d] = clist[b * L + d];
    __syncthreads();
    int len = clen[b];
    int nl = len < L ? len : L;
    float a0 = 0.f, a1 = 0.f, a2 = 0.f, a3 = 0.f;
    int l = 0;
    for (; l + 4 <= nl; l += 4) {
        a0 += embw[(size_t)cl[l]     * D + d];
        a1 += embw[(size_t)cl[l + 1] * D + d];
        a2 += embw[(size_t)cl[l + 2] * D + d];
        a3 += embw[(size_t)cl[l + 3] * D + d];
    }
    for (; l < nl; ++l) a0 += embw[(size_t)cl[l] * D + d];
    float denom = (float)(len < 1 ? 1 : len);
    part[b * D + d] = (a0 + a1 + a2 + a3) / denom;
}

// ---------------- kernel 1b: ctx[d] = mean_b part[b,d] ----------------
__global__ void k1b_reduce(const float* __restrict__ part, float* __restrict__ ctx) {
    int d = threadIdx.x;
    float s = 0.f;
    #pragma unroll 8
    for (int b = 0; b < B; ++b) s += part[b * D + d];
    ctx[d] = s * (1.0f / (float)B);
}

// ---------------- kernel 2: w1 = 5*lam*cos, w0 = 5*(1-lam)*aff; zero A ----------------
__global__ __launch_bounds__(256) void k2_cos(const float* __restrict__ kb,
                                              const float* __restrict__ lam,
                                              const float* __restrict__ aff,
                                              const float* __restrict__ ctx,
                                              float* __restrict__ w1,
                                              float* __restrict__ w0,
                                              float* __restrict__ A) {
    int tid = threadIdx.x;
    int gtid = blockIdx.x * 256 + tid;
    A[gtid] = 0.f;   // grid covers B*V exactly

    __shared__ float ctxs[D];
    __shared__ float red[5];
    int wid = tid >> 6, lane = tid & 63;
    float c = ctx[tid];
    ctxs[tid] = c;
    float sq = c * c;
    #pragma unroll
    for (int o = 32; o > 0; o >>= 1) sq += __shfl_xor(sq, o);
    if (lane == 0) red[wid] = sq;
    __syncthreads();
    if (tid == 0) red[4] = sqrtf(red[0] + red[1] + red[2] + red[3]);
    __syncthreads();
    float ctxnorm = red[4];

    int v = blockIdx.x * 4 + wid;   // one wave per v
    float4 k4 = *(const float4*)(kb + (size_t)v * D + lane * 4);
    float4 c4 = *(const float4*)(ctxs + lane * 4);
    float dot = k4.x * c4.x + k4.y * c4.y + k4.z * c4.z + k4.w * c4.w;
    float sqs = k4.x * k4.x + k4.y * k4.y + k4.z * k4.z + k4.w * k4.w;
    #pragma unroll
    for (int o = 32; o > 0; o >>= 1) {
        dot += __shfl_xor(dot, o);
        sqs += __shfl_xor(sqs, o);
    }
    if (lane == 0) {
        float cosv = fabsf(dot) / fmaxf(sqrtf(sqs) * ctxnorm, 1e-8f);
        float la = lam[v];
        w1[v] = 5.0f * la * cosv;
        w0[v] = 5.0f * (1.0f - la) * aff[v];
    }
}

// ---------------- kernel 3: per-(b,split) softmax over V, accumulate A[b,v] --------
__global__ __launch_bounds__(1024) void k3_softmax(
    const int* __restrict__ clist, const int* __restrict__ clen,
    const int* __restrict__ cmask, const float* __restrict__ edge,
    const float* __restrict__ w1g, const float* __restrict__ w0g,
    float* __restrict__ A) {
    int b = blockIdx.x, split = blockIdx.y;
    int tid = threadIdx.x;
    int wid = tid >> 6, lane = tid & 63;
    bool active = tid < (V / 8);     // 1000 active threads cover 8000 v's
    int v0 = tid * 8;
    __shared__ float lsum[2][16];

    float w1r[8], w0r[8], acc[8];
    int mr[8];
    if (active) {
        float4 t0 = *(const float4*)(w1g + v0);
        float4 t1 = *(const float4*)(w1g + v0 + 4);
        w1r[0]=t0.x; w1r[1]=t0.y; w1r[2]=t0.z; w1r[3]=t0.w;
        w1r[4]=t1.x; w1r[5]=t1.y; w1r[6]=t1.z; w1r[7]=t1.w;
        t0 = *(const float4*)(w0g + v0);
        t1 = *(const float4*)(w0g + v0 + 4);
        w0r[0]=t0.x; w0r[1]=t0.y; w0r[2]=t0.z; w0r[3]=t0.w;
        w0r[4]=t1.x; w0r[5]=t1.y; w0r[6]=t1.z; w0r[7]=t1.w;
        int4 m0 = *(const int4*)(cmask + (size_t)b * V + v0);
        int4 m1 = *(const int4*)(cmask + (size_t)b * V + v0 + 4);
        mr[0]=m0.x; mr[1]=m0.y; mr[2]=m0.z; mr[3]=m0.w;
        mr[4]=m1.x; mr[5]=m1.y; mr[6]=m1.z; mr[7]=m1.w;
    }
    #pragma unroll
    for (int j = 0; j < 8; ++j) acc[j] = 0.f;

    int len = clen[b];
    int nl = len < L ? len : L;
    int parity = 0;
    for (int l = split; l < nl; l += SPLIT) {
        int c = clist[b * L + l];
        const float* er = edge + (size_t)c * V;
        // w = w1*e + (e>0)*w0 is bounded by ~5.01 -> exp() safe, no max pass
        float p[8];
        float s = 0.f;
        if (active) {
            float4 e0 = *(const float4*)(er + v0);
            float4 e1 = *(const float4*)(er + v0 + 4);
            float ev[8] = {e0.x, e0.y, e0.z, e0.w, e1.x, e1.y, e1.z, e1.w};
            #pragma unroll
            for (int j = 0; j < 8; ++j) {
                float e = ev[j];
                float wv = w1r[j] * e + (e > 0.f ? w0r[j] : 0.f);
                wv = (mr[j] != 0) ? wv : 5e-9f;   // (1e-9 masked) * concentration 5
                p[j] = __expf(wv);
                s += p[j];
            }
        } else {
            #pragma unroll
            for (int j = 0; j < 8; ++j) p[j] = 0.f;
        }
        #pragma unroll
        for (int o = 32; o > 0; o >>= 1) s += __shfl_xor(s, o);
        if (lane == 0) lsum[parity][wid] = s;
        __syncthreads();
        float tot = 0.f;
        #pragma unroll
        for (int k = 0; k < 16; ++k) tot += lsum[parity][k];
        float inv = 1.0f / tot;
        if (active) {
            #pragma unroll
            for (int j = 0; j < 8; ++j) acc[j] += p[j] * inv;
        }
        parity ^= 1;
    }
    if (active) {
        #pragma unroll
        for (int j = 0; j < 8; ++j)
            atomicAdd(&A[(size_t)b * V + v0 + j], acc[j]);
    }
}

// ---------------- kernel 4: P[ch,b,d] = sum_{v in chunk} A[b,v]*KB[v,d] ----------------
__global__ __launch_bounds__(256) void k4_gemv(const float* __restrict__ A,
                                               const float* __restrict__ kb,
                                               float* __restrict__ P) {
    int ch = blockIdx.x;     // 0..NCH-1
    int tid = threadIdx.x;   // = d
    int vbase = ch * VC;
    __shared__ float Al[B][VC];
    for (int i = tid; i < B * VC; i += 256) {
        int bt = i / VC, vl = i % VC;
        Al[bt][vl] = A[(size_t)bt * V + vbase + vl];
    }
    __syncthreads();
    float acc[B];
    #pragma unroll
    for (int t = 0; t < B; ++t) acc[t] = 0.f;
    for (int vl = 0; vl < VC; ++vl) {
        float kv = kb[(size_t)(vbase + vl) * D + tid];
        #pragma unroll
        for (int t = 0; t < B; ++t) acc[t] += Al[t][vl] * kv;
    }
    #pragma unroll
    for (int t = 0; t < B; ++t)
        P[(size_t)ch * (B * D) + (size_t)t * D + tid] = acc[t];
}

// ---------------- kernel 5: out0[b,d] = sum_ch P[ch,b,d] / denom_b ----------------
__global__ void k5_out0(const float* __restrict__ P, const int* __restrict__ clen,
                        float* __restrict__ out0) {
    int b = blockIdx.x, d = threadIdx.x;
    float s = 0.f;
    #pragma unroll 8
    for (int ch = 0; ch < NCH; ++ch) s += P[(size_t)ch * (B * D) + b * D + d];
    int len = clen[b];
    out0[b * D + d] = s / (float)(len < 1 ? 1 : len);
}

// ---------------- kernel 6: GLOBALLY-LINEAR broadcast kb -> out1 ----------------
// Mimics fillBufferAligned exactly: consecutive blocks write consecutive 4 KB
// chunks of one linear 524 MB sweep (no 8 MB-strided concurrent streams).
// Each thread writes 4 consecutive float4 (64 B). src row index via constant
// division (magic-mul); all 4 elements stay within one row (ROW4 % 4 == 0).
__global__ __launch_bounds__(256) void k6_bcast(const f32x4* __restrict__ kb4,
                                                f32x4* __restrict__ out4) {
    unsigned int t = (blockIdx.x * 256u + threadIdx.x) * 4u;   // float4 index
    unsigned int b = t / ROW4;                                  // constant divisor
    unsigned int off = t - b * ROW4;
    const f32x4* src = kb4 + off;
    f32x4* dst = out4 + (size_t)t;
    #pragma unroll
    for (int i = 0; i < 4; ++i)
        __builtin_nontemporal_store(src[i], &dst[i]);
}

extern "C" void kernel_launch(void* const* d_in, const int* in_sizes, int n_in,
                              void* d_out, int out_size, void* d_ws, size_t ws_size,
                              hipStream_t stream) {
    const int*   clist = (const int*)d_in[0];
    const int*   clen  = (const int*)d_in[1];
    const int*   cmask = (const int*)d_in[2];
    const float* edge  = (const float*)d_in[3];
    const float* aff   = (const float*)d_in[4];
    const float* embw  = (const float*)d_in[5];
    const float* kb    = (const float*)d_in[6];
    const float* lam   = (const float*)d_in[7];
    float* out0 = (float*)d_out;
    float* out1 = out0 + B * D;
    float* ws   = (float*)d_ws;

    k1_ctx<<<dim3(B), dim3(256), 0, stream>>>(clist, clen, embw, ws + PART_OFF);
    k1b_reduce<<<dim3(1), dim3(D), 0, stream>>>(ws + PART_OFF, ws + CTX_OFF);
    k2_cos<<<dim3(V / 4), dim3(256), 0, stream>>>(kb, lam, aff, ws + CTX_OFF,
                                                  ws + W1_OFF, ws + W0_OFF, ws + A_OFF);
    k3_softmax<<<dim3(B, SPLIT), dim3(1024), 0, stream>>>(clist, clen, cmask, edge,
                                                          ws + W1_OFF, ws + W0_OFF, ws + A_OFF);
    k4_gemv<<<dim3(NCH), dim3(256), 0, stream>>>(ws + A_OFF, kb, ws + P_OFF);
    k5_out0<<<dim3(B), dim3(D), 0, stream>>>(ws + P_OFF, clen, out0);
    // B*V*D/4 float4 total / (256 threads * 4 per thread) = 32000 blocks
    k6_bcast<<<dim3(B * ROW4 / 1024), dim3(256), 0, stream>>>((const f32x4*)kb,
                                                              (f32x4*)out1);
}

// Round 6
// 268.789 us; speedup vs baseline: 3.3450x; 3.3450x over previous
//
#include <hip/hip_runtime.h>
#include <cstddef>
#include <cstdint>
#include <cmath>

#define V 8000
#define D 256
#define B 64
#define L 64
#define SPLIT 4
#define NCH 200
#define VC 40                      // NCH*VC = V
#define ROW4 (V * D / 4)           // 512000 float4 per batch row

// ws layout (float offsets) — nothing needs host-side zeroing
#define PART_OFF 0         // [B*D]
#define CTX_OFF  16384     // [D]
#define W1_OFF   16640     // [V]
#define W0_OFF   24640     // [V]
#define A_OFF    32640     // [B*V] zeroed by k2
#define P_OFF    544640    // [NCH*B*D] fully overwritten by k4

typedef float f32x4 __attribute__((ext_vector_type(4)));

// ---------------- kernel 1: per-batch masked row mean -> part[b,d] ----------------
__global__ __launch_bounds__(256) void k1_ctx(const int* __restrict__ clist,
                                              const int* __restrict__ clen,
                                              const float* __restrict__ embw,
                                              float* __restrict__ part) {
    int b = blockIdx.x, d = threadIdx.x;
    __shared__ int cl[L];
    if (d < L) cl[d] = clist[b * L + d];
    __syncthreads();
    int len = clen[b];
    int nl = len < L ? len : L;
    float a0 = 0.f, a1 = 0.f, a2 = 0.f, a3 = 0.f;
    int l = 0;
    for (; l + 4 <= nl; l += 4) {
        a0 += embw[(size_t)cl[l]     * D + d];
        a1 += embw[(size_t)cl[l + 1] * D + d];
        a2 += embw[(size_t)cl[l + 2] * D + d];
        a3 += embw[(size_t)cl[l + 3] * D + d];
    }
    for (; l < nl; ++l) a0 += embw[(size_t)cl[l] * D + d];
    float denom = (float)(len < 1 ? 1 : len);
    part[b * D + d] = (a0 + a1 + a2 + a3) / denom;
}

// ---------------- kernel 1b: ctx[d] = mean_b part[b,d] ----------------
__global__ void k1b_reduce(const float* __restrict__ part, float* __restrict__ ctx) {
    int d = threadIdx.x;
    float s = 0.f;
    #pragma unroll 8
    for (int b = 0; b < B; ++b) s += part[b * D + d];
    ctx[d] = s * (1.0f / (float)B);
}

// ---------------- kernel 2: w1 = 5*lam*cos, w0 = 5*(1-lam)*aff; zero A ----------------
__global__ __launch_bounds__(256) void k2_cos(const float* __restrict__ kb,
                                              const float* __restrict__ lam,
                                              const float* __restrict__ aff,
                                              const float* __restrict__ ctx,
                                              float* __restrict__ w1,
                                              float* __restrict__ w0,
                                              float* __restrict__ A) {
    int tid = threadIdx.x;
    int gtid = blockIdx.x * 256 + tid;
    A[gtid] = 0.f;   // grid covers B*V exactly

    __shared__ float ctxs[D];
    __shared__ float red[5];
    int wid = tid >> 6, lane = tid & 63;
    float c = ctx[tid];
    ctxs[tid] = c;
    float sq = c * c;
    #pragma unroll
    for (int o = 32; o > 0; o >>= 1) sq += __shfl_xor(sq, o);
    if (lane == 0) red[wid] = sq;
    __syncthreads();
    if (tid == 0) red[4] = sqrtf(red[0] + red[1] + red[2] + red[3]);
    __syncthreads();
    float ctxnorm = red[4];

    int v = blockIdx.x * 4 + wid;   // one wave per v
    float4 k4 = *(const float4*)(kb + (size_t)v * D + lane * 4);
    float4 c4 = *(const float4*)(ctxs + lane * 4);
    float dot = k4.x * c4.x + k4.y * c4.y + k4.z * c4.z + k4.w * c4.w;
    float sqs = k4.x * k4.x + k4.y * k4.y + k4.z * k4.z + k4.w * k4.w;
    #pragma unroll
    for (int o = 32; o > 0; o >>= 1) {
        dot += __shfl_xor(dot, o);
        sqs += __shfl_xor(sqs, o);
    }
    if (lane == 0) {
        float cosv = fabsf(dot) / fmaxf(sqrtf(sqs) * ctxnorm, 1e-8f);
        float la = lam[v];
        w1[v] = 5.0f * la * cosv;
        w0[v] = 5.0f * (1.0f - la) * aff[v];
    }
}

// ---------------- kernel 3: per-(b,split) softmax over V, accumulate A[b,v] --------
__global__ __launch_bounds__(1024) void k3_softmax(
    const int* __restrict__ clist, const int* __restrict__ clen,
    const int* __restrict__ cmask, const float* __restrict__ edge,
    const float* __restrict__ w1g, const float* __restrict__ w0g,
    float* __restrict__ A) {
    int b = blockIdx.x, split = blockIdx.y;
    int tid = threadIdx.x;
    int wid = tid >> 6, lane = tid & 63;
    bool active = tid < (V / 8);     // 1000 active threads cover 8000 v's
    int v0 = tid * 8;
    __shared__ float lsum[2][16];

    float w1r[8], w0r[8], acc[8];
    int mr[8];
    if (active) {
        float4 t0 = *(const float4*)(w1g + v0);
        float4 t1 = *(const float4*)(w1g + v0 + 4);
        w1r[0]=t0.x; w1r[1]=t0.y; w1r[2]=t0.z; w1r[3]=t0.w;
        w1r[4]=t1.x; w1r[5]=t1.y; w1r[6]=t1.z; w1r[7]=t1.w;
        t0 = *(const float4*)(w0g + v0);
        t1 = *(const float4*)(w0g + v0 + 4);
        w0r[0]=t0.x; w0r[1]=t0.y; w0r[2]=t0.z; w0r[3]=t0.w;
        w0r[4]=t1.x; w0r[5]=t1.y; w0r[6]=t1.z; w0r[7]=t1.w;
        int4 m0 = *(const int4*)(cmask + (size_t)b * V + v0);
        int4 m1 = *(const int4*)(cmask + (size_t)b * V + v0 + 4);
        mr[0]=m0.x; mr[1]=m0.y; mr[2]=m0.z; mr[3]=m0.w;
        mr[4]=m1.x; mr[5]=m1.y; mr[6]=m1.z; mr[7]=m1.w;
    }
    #pragma unroll
    for (int j = 0; j < 8; ++j) acc[j] = 0.f;

    int len = clen[b];
    int nl = len < L ? len : L;
    int parity = 0;
    for (int l = split; l < nl; l += SPLIT) {
        int c = clist[b * L + l];
        const float* er = edge + (size_t)c * V;
        // w = w1*e + (e>0)*w0 is bounded by ~5.01 -> exp() safe, no max pass
        float p[8];
        float s = 0.f;
        if (active) {
            float4 e0 = *(const float4*)(er + v0);
            float4 e1 = *(const float4*)(er + v0 + 4);
            float ev[8] = {e0.x, e0.y, e0.z, e0.w, e1.x, e1.y, e1.z, e1.w};
            #pragma unroll
            for (int j = 0; j < 8; ++j) {
                float e = ev[j];
                float wv = w1r[j] * e + (e > 0.f ? w0r[j] : 0.f);
                wv = (mr[j] != 0) ? wv : 5e-9f;   // (1e-9 masked) * concentration 5
                p[j] = __expf(wv);
                s += p[j];
            }
        } else {
            #pragma unroll
            for (int j = 0; j < 8; ++j) p[j] = 0.f;
        }
        #pragma unroll
        for (int o = 32; o > 0; o >>= 1) s += __shfl_xor(s, o);
        if (lane == 0) lsum[parity][wid] = s;
        __syncthreads();
        float tot = 0.f;
        #pragma unroll
        for (int k = 0; k < 16; ++k) tot += lsum[parity][k];
        float inv = 1.0f / tot;
        if (active) {
            #pragma unroll
            for (int j = 0; j < 8; ++j) acc[j] += p[j] * inv;
        }
        parity ^= 1;
    }
    if (active) {
        #pragma unroll
        for (int j = 0; j < 8; ++j)
            atomicAdd(&A[(size_t)b * V + v0 + j], acc[j]);
    }
}

// ---------------- kernel 4: P[ch,b,d] = sum_{v in chunk} A[b,v]*KB[v,d] ----------------
__global__ __launch_bounds__(256) void k4_gemv(const float* __restrict__ A,
                                               const float* __restrict__ kb,
                                               float* __restrict__ P) {
    int ch = blockIdx.x;     // 0..NCH-1
    int tid = threadIdx.x;   // = d
    int vbase = ch * VC;
    __shared__ float Al[B][VC];
    for (int i = tid; i < B * VC; i += 256) {
        int bt = i / VC, vl = i % VC;
        Al[bt][vl] = A[(size_t)bt * V + vbase + vl];
    }
    __syncthreads();
    float acc[B];
    #pragma unroll
    for (int t = 0; t < B; ++t) acc[t] = 0.f;
    for (int vl = 0; vl < VC; ++vl) {
        float kv = kb[(size_t)(vbase + vl) * D + tid];
        #pragma unroll
        for (int t = 0; t < B; ++t) acc[t] += Al[t][vl] * kv;
    }
    #pragma unroll
    for (int t = 0; t < B; ++t)
        P[(size_t)ch * (B * D) + (size_t)t * D + tid] = acc[t];
}

// ---------------- kernel 5: out0[b,d] = sum_ch P[ch,b,d] / denom_b ----------------
__global__ void k5_out0(const float* __restrict__ P, const int* __restrict__ clen,
                        float* __restrict__ out0) {
    int b = blockIdx.x, d = threadIdx.x;
    float s = 0.f;
    #pragma unroll 8
    for (int ch = 0; ch < NCH; ++ch) s += P[(size_t)ch * (B * D) + b * D + d];
    int len = clen[b];
    out0[b * D + d] = s / (float)(len < 1 ? 1 : len);
}

// ---------------- kernel 6: broadcast kb -> out1 (per-instruction coalesced) -------
// Each thread owns ONE float4 column index (wave lanes contiguous -> 1KB/store
// coalescing, the round-1 pattern that ran ~5.6 TB/s) and loops the 64 rows.
// Row order is rotated per block so the grid's write streams spread across all
// 64 rows at any instant instead of marching in 8MB-aliased lockstep.
__global__ __launch_bounds__(256) void k6_bcast(const f32x4* __restrict__ kb4,
                                                f32x4* __restrict__ out4) {
    int idx = blockIdx.x * 256 + threadIdx.x;   // [0, ROW4), grid covers exactly
    f32x4 f = kb4[idx];
    int bstart = blockIdx.x & (B - 1);
    #pragma unroll
    for (int bb = 0; bb < B; ++bb) {
        int b = (bb + bstart) & (B - 1);
        __builtin_nontemporal_store(f, &out4[(size_t)b * ROW4 + idx]);
    }
}

extern "C" void kernel_launch(void* const* d_in, const int* in_sizes, int n_in,
                              void* d_out, int out_size, void* d_ws, size_t ws_size,
                              hipStream_t stream) {
    const int*   clist = (const int*)d_in[0];
    const int*   clen  = (const int*)d_in[1];
    const int*   cmask = (const int*)d_in[2];
    const float* edge  = (const float*)d_in[3];
    const float* aff   = (const float*)d_in[4];
    const float* embw  = (const float*)d_in[5];
    const float* kb    = (const float*)d_in[6];
    const float* lam   = (const float*)d_in[7];
    float* out0 = (float*)d_out;
    float* out1 = out0 + B * D;
    float* ws   = (float*)d_ws;

    k1_ctx<<<dim3(B), dim3(256), 0, stream>>>(clist, clen, embw, ws + PART_OFF);
    k1b_reduce<<<dim3(1), dim3(D), 0, stream>>>(ws + PART_OFF, ws + CTX_OFF);
    k2_cos<<<dim3(V / 4), dim3(256), 0, stream>>>(kb, lam, aff, ws + CTX_OFF,
                                                  ws + W1_OFF, ws + W0_OFF, ws + A_OFF);
    k3_softmax<<<dim3(B, SPLIT), dim3(1024), 0, stream>>>(clist, clen, cmask, edge,
                                                          ws + W1_OFF, ws + W0_OFF, ws + A_OFF);
    k4_gemv<<<dim3(NCH), dim3(256), 0, stream>>>(ws + A_OFF, kb, ws + P_OFF);
    k5_out0<<<dim3(B), dim3(D), 0, stream>>>(ws + P_OFF, clen, out0);
    k6_bcast<<<dim3(ROW4 / 256), dim3(256), 0, stream>>>((const f32x4*)kb,
                                                         (f32x4*)out1);
}

// Round 7
// 257.136 us; speedup vs baseline: 3.4966x; 1.0453x over previous
//
#include <hip/hip_runtime.h>
#include <cstddef>
#include <cstdint>
#include <cmath>

#define V 8000
#define D 256
#define B 64
#define L 64
#define SPLIT 4
#define NCH 200
#define VC 40                      // NCH*VC = V
#define ROW4 (V * D / 4)           // 512000 float4 per batch row

// ws layout (float offsets) — nothing needs host-side zeroing
#define PART_OFF 0         // [B*D]
#define W1_OFF   16384     // [V]
#define W0_OFF   24384     // [V]
#define A_OFF    32384     // [B*V] zeroed by k2

typedef float f32x4 __attribute__((ext_vector_type(4)));

// ---------------- kernel 1: per-batch masked row mean -> part[b,d] ----------------
__global__ __launch_bounds__(256) void k1_ctx(const int* __restrict__ clist,
                                              const int* __restrict__ clen,
                                              const float* __restrict__ embw,
                                              float* __restrict__ part) {
    int b = blockIdx.x, d = threadIdx.x;
    __shared__ int cl[L];
    if (d < L) cl[d] = clist[b * L + d];
    __syncthreads();
    int len = clen[b];
    int nl = len < L ? len : L;
    float a0 = 0.f, a1 = 0.f, a2 = 0.f, a3 = 0.f;
    int l = 0;
    for (; l + 4 <= nl; l += 4) {
        a0 += embw[(size_t)cl[l]     * D + d];
        a1 += embw[(size_t)cl[l + 1] * D + d];
        a2 += embw[(size_t)cl[l + 2] * D + d];
        a3 += embw[(size_t)cl[l + 3] * D + d];
    }
    for (; l < nl; ++l) a0 += embw[(size_t)cl[l] * D + d];
    float denom = (float)(len < 1 ? 1 : len);
    part[b * D + d] = (a0 + a1 + a2 + a3) / denom;
}

// ---- kernel 2: ctx (per-block redundant reduce of part, L2-resident),
//      w1 = 5*lam*cos, w0 = 5*(1-lam)*aff; zeroes A and out0 ----
__global__ __launch_bounds__(256) void k2_cos(const float* __restrict__ kb,
                                              const float* __restrict__ lam,
                                              const float* __restrict__ aff,
                                              const float* __restrict__ part,
                                              float* __restrict__ w1,
                                              float* __restrict__ w0,
                                              float* __restrict__ A,
                                              float* __restrict__ out0) {
    int tid = threadIdx.x;
    int gtid = blockIdx.x * 256 + tid;
    A[gtid] = 0.f;                      // grid covers B*V exactly
    if (gtid < B * D) out0[gtid] = 0.f; // zero for k4's atomic accumulation

    __shared__ float ctxs[D];
    __shared__ float red[5];
    // ctx[tid] = mean_b part[b,tid]  (part is 64KB, L2-resident after k1)
    float s = 0.f;
    #pragma unroll 8
    for (int b = 0; b < B; ++b) s += part[b * D + tid];
    float c = s * (1.0f / (float)B);
    ctxs[tid] = c;

    int wid = tid >> 6, lane = tid & 63;
    float sq = c * c;
    #pragma unroll
    for (int o = 32; o > 0; o >>= 1) sq += __shfl_xor(sq, o);
    if (lane == 0) red[wid] = sq;
    __syncthreads();
    if (tid == 0) red[4] = sqrtf(red[0] + red[1] + red[2] + red[3]);
    __syncthreads();
    float ctxnorm = red[4];

    int v = blockIdx.x * 4 + wid;   // one wave per v
    float4 k4 = *(const float4*)(kb + (size_t)v * D + lane * 4);
    float4 c4 = *(const float4*)(ctxs + lane * 4);
    float dot = k4.x * c4.x + k4.y * c4.y + k4.z * c4.z + k4.w * c4.w;
    float sqs = k4.x * k4.x + k4.y * k4.y + k4.z * k4.z + k4.w * k4.w;
    #pragma unroll
    for (int o = 32; o > 0; o >>= 1) {
        dot += __shfl_xor(dot, o);
        sqs += __shfl_xor(sqs, o);
    }
    if (lane == 0) {
        float cosv = fabsf(dot) / fmaxf(sqrtf(sqs) * ctxnorm, 1e-8f);
        float la = lam[v];
        w1[v] = 5.0f * la * cosv;
        w0[v] = 5.0f * (1.0f - la) * aff[v];
    }
}

// ---------------- kernel 3: per-(b,split) softmax over V, accumulate A[b,v] --------
__global__ __launch_bounds__(1024) void k3_softmax(
    const int* __restrict__ clist, const int* __restrict__ clen,
    const int* __restrict__ cmask, const float* __restrict__ edge,
    const float* __restrict__ w1g, const float* __restrict__ w0g,
    float* __restrict__ A) {
    int b = blockIdx.x, split = blockIdx.y;
    int tid = threadIdx.x;
    int wid = tid >> 6, lane = tid & 63;
    bool active = tid < (V / 8);     // 1000 active threads cover 8000 v's
    int v0 = tid * 8;
    __shared__ float lsum[2][16];

    float w1r[8], w0r[8], acc[8];
    int mr[8];
    if (active) {
        float4 t0 = *(const float4*)(w1g + v0);
        float4 t1 = *(const float4*)(w1g + v0 + 4);
        w1r[0]=t0.x; w1r[1]=t0.y; w1r[2]=t0.z; w1r[3]=t0.w;
        w1r[4]=t1.x; w1r[5]=t1.y; w1r[6]=t1.z; w1r[7]=t1.w;
        t0 = *(const float4*)(w0g + v0);
        t1 = *(const float4*)(w0g + v0 + 4);
        w0r[0]=t0.x; w0r[1]=t0.y; w0r[2]=t0.z; w0r[3]=t0.w;
        w0r[4]=t1.x; w0r[5]=t1.y; w0r[6]=t1.z; w0r[7]=t1.w;
        int4 m0 = *(const int4*)(cmask + (size_t)b * V + v0);
        int4 m1 = *(const int4*)(cmask + (size_t)b * V + v0 + 4);
        mr[0]=m0.x; mr[1]=m0.y; mr[2]=m0.z; mr[3]=m0.w;
        mr[4]=m1.x; mr[5]=m1.y; mr[6]=m1.z; mr[7]=m1.w;
    }
    #pragma unroll
    for (int j = 0; j < 8; ++j) acc[j] = 0.f;

    int len = clen[b];
    int nl = len < L ? len : L;
    int parity = 0;
    for (int l = split; l < nl; l += SPLIT) {
        int c = clist[b * L + l];
        const float* er = edge + (size_t)c * V;
        // w = w1*e + (e>0)*w0 is bounded by ~5.01 -> exp() safe, no max pass
        float p[8];
        float s = 0.f;
        if (active) {
            float4 e0 = *(const float4*)(er + v0);
            float4 e1 = *(const float4*)(er + v0 + 4);
            float ev[8] = {e0.x, e0.y, e0.z, e0.w, e1.x, e1.y, e1.z, e1.w};
            #pragma unroll
            for (int j = 0; j < 8; ++j) {
                float e = ev[j];
                float wv = w1r[j] * e + (e > 0.f ? w0r[j] : 0.f);
                wv = (mr[j] != 0) ? wv : 5e-9f;   // (1e-9 masked) * concentration 5
                p[j] = __expf(wv);
                s += p[j];
            }
        } else {
            #pragma unroll
            for (int j = 0; j < 8; ++j) p[j] = 0.f;
        }
        #pragma unroll
        for (int o = 32; o > 0; o >>= 1) s += __shfl_xor(s, o);
        if (lane == 0) lsum[parity][wid] = s;
        __syncthreads();
        float tot = 0.f;
        #pragma unroll
        for (int k = 0; k < 16; ++k) tot += lsum[parity][k];
        float inv = 1.0f / tot;
        if (active) {
            #pragma unroll
            for (int j = 0; j < 8; ++j) acc[j] += p[j] * inv;
        }
        parity ^= 1;
    }
    if (active) {
        #pragma unroll
        for (int j = 0; j < 8; ++j)
            atomicAdd(&A[(size_t)b * V + v0 + j], acc[j]);
    }
}

// ---- kernel 4: out0[b,d] += (sum_{v in chunk} A[b,v]*KB[v,d]) / denom_b ----
// P intermediate eliminated: each chunk block atomically accumulates its
// contribution (out0 zeroed by k2; stream order guarantees k2 < k4).
__global__ __launch_bounds__(256) void k4_gemv(const float* __restrict__ A,
                                               const float* __restrict__ kb,
                                               const int* __restrict__ clen,
                                               float* __restrict__ out0) {
    int ch = blockIdx.x;     // 0..NCH-1
    int tid = threadIdx.x;   // = d
    int vbase = ch * VC;
    __shared__ float Al[B][VC];
    __shared__ float inv[B];
    if (tid < B) {
        int len = clen[tid];
        inv[tid] = 1.0f / (float)(len < 1 ? 1 : len);
    }
    for (int i = tid; i < B * VC; i += 256) {
        int bt = i / VC, vl = i % VC;
        Al[bt][vl] = A[(size_t)bt * V + vbase + vl];
    }
    __syncthreads();
    float acc[B];
    #pragma unroll
    for (int t = 0; t < B; ++t) acc[t] = 0.f;
    for (int vl = 0; vl < VC; ++vl) {
        float kv = kb[(size_t)(vbase + vl) * D + tid];
        #pragma unroll
        for (int t = 0; t < B; ++t) acc[t] += Al[t][vl] * kv;
    }
    #pragma unroll
    for (int t = 0; t < B; ++t)
        atomicAdd(&out0[t * D + tid], acc[t] * inv[t]);
}

// ---------------- kernel 6: broadcast kb -> out1 (per-instruction coalesced) -------
// Each thread owns ONE float4 column index (wave lanes contiguous -> 1KB/store
// coalescing); loops 64 rows with per-block row-phase rotation so write streams
// spread across all rows instead of marching in 8MB-aliased lockstep.
__global__ __launch_bounds__(256) void k6_bcast(const f32x4* __restrict__ kb4,
                                                f32x4* __restrict__ out4) {
    int idx = blockIdx.x * 256 + threadIdx.x;   // [0, ROW4), grid covers exactly
    f32x4 f = kb4[idx];
    int bstart = blockIdx.x & (B - 1);
    #pragma unroll
    for (int bb = 0; bb < B; ++bb) {
        int b = (bb + bstart) & (B - 1);
        __builtin_nontemporal_store(f, &out4[(size_t)b * ROW4 + idx]);
    }
}

extern "C" void kernel_launch(void* const* d_in, const int* in_sizes, int n_in,
                              void* d_out, int out_size, void* d_ws, size_t ws_size,
                              hipStream_t stream) {
    const int*   clist = (const int*)d_in[0];
    const int*   clen  = (const int*)d_in[1];
    const int*   cmask = (const int*)d_in[2];
    const float* edge  = (const float*)d_in[3];
    const float* aff   = (const float*)d_in[4];
    const float* embw  = (const float*)d_in[5];
    const float* kb    = (const float*)d_in[6];
    const float* lam   = (const float*)d_in[7];
    float* out0 = (float*)d_out;
    float* out1 = out0 + B * D;
    float* ws   = (float*)d_ws;

    k1_ctx<<<dim3(B), dim3(256), 0, stream>>>(clist, clen, embw, ws + PART_OFF);
    k2_cos<<<dim3(V / 4), dim3(256), 0, stream>>>(kb, lam, aff, ws + PART_OFF,
                                                  ws + W1_OFF, ws + W0_OFF,
                                                  ws + A_OFF, out0);
    k3_softmax<<<dim3(B, SPLIT), dim3(1024), 0, stream>>>(clist, clen, cmask, edge,
                                                          ws + W1_OFF, ws + W0_OFF, ws + A_OFF);
    k4_gemv<<<dim3(NCH), dim3(256), 0, stream>>>(ws + A_OFF, kb, clen, out0);
    k6_bcast<<<dim3(ROW4 / 256), dim3(256), 0, stream>>>((const f32x4*)kb,
                                                         (f32x4*)out1);
}